// Round 7
// baseline (238.800 us; speedup 1.0000x reference)
//
#include <hip/hip_runtime.h>

// All inputs and the output are float32 (established rounds 0-3).
// R14 = R13 resubmitted verbatim after a second infra flake ("container failed
// twice" -- same signature as R9's flake; R10's verbatim resubmit then passed).
// Audit: shared_kernel barriers are block-uniform, all indexing in bounds,
// VGPR envelope comfortable, ws 385KB, no forbidden host APIs.
// R13 rationale: totals (234->240->247->229) barely track mega (83->67->74->68):
// ~155us fixed cost that isn't mega -- looks like per-dispatch overhead. This
// round removes a dispatch at zero algorithmic cost: l1+l2re fused into one
// per-batch-row shared_kernel (block b: stage h[b] -> hid=leaky(h@st_w1+b1) ->
// sh[b]=hid@st_w2+b2; blocks 64..87: prebias re[r]). mega/depth = R12 verbatim.

__device__ __forceinline__ float leaky(float v) { return v >= 0.f ? v : 0.2f * v; }

// ---------- D0: shared MLP + prebias. 88 blocks x 512 thr.
// blocks 0..63 (b=blk): sh[b] = leaky(h[b] @ st_w1 + st_b1) @ st_w2 + st_b2
// blocks 64..87 (r=blk-64): re[r] = rm_b1[r] + rank_emb[r] @ rm_w1[r, 256:, :]
__global__ __launch_bounds__(512, 2) void shared_kernel(
    const float* __restrict__ h,
    const float* __restrict__ st_w1, const float* __restrict__ st_b1,
    const float* __restrict__ st_w2, const float* __restrict__ st_b2,
    const float* __restrict__ rank_emb,
    const float* __restrict__ rm_w1, const float* __restrict__ rm_b1,
    float* __restrict__ sh, float* __restrict__ re)
{
    __shared__ __align__(16) float h_s[768];
    __shared__ __align__(16) float hid_s[512];
    __shared__ __align__(16) float ps[2][256];
    const int tid = threadIdx.x;
    const int blk = blockIdx.x;
    if (blk < 64) {
        const int b = blk;
        if (tid < 192)
            ((float4*)h_s)[tid] = ((const float4*)(h + (size_t)b * 768))[tid];
        __syncthreads();
        // hid[col] = leaky(st_b1[col] + sum_k h_s[k] * st_w1[k*512+col])
        {
            const int col = tid;
            float acc0 = st_b1[col], acc1 = 0.f;   // dual acc: break 768-FMA chain
            const float* wp = st_w1 + col;
            #pragma unroll 4
            for (int k = 0; k < 768; k += 8) {
                float w0 = wp[(size_t)(k + 0) * 512], w1 = wp[(size_t)(k + 1) * 512];
                float w2 = wp[(size_t)(k + 2) * 512], w3 = wp[(size_t)(k + 3) * 512];
                float4 hv0 = *(const float4*)&h_s[k];
                float w4 = wp[(size_t)(k + 4) * 512], w5 = wp[(size_t)(k + 5) * 512];
                float w6 = wp[(size_t)(k + 6) * 512], w7 = wp[(size_t)(k + 7) * 512];
                float4 hv1 = *(const float4*)&h_s[k + 4];
                acc0 += hv0.x * w0 + hv0.y * w1 + hv0.z * w2 + hv0.w * w3;
                acc1 += hv1.x * w4 + hv1.y * w5 + hv1.z * w6 + hv1.w * w7;
            }
            hid_s[col] = leaky(acc0 + acc1);
        }
        __syncthreads();
        // sh[b][c] = st_b2[c] + hid @ st_w2[:,c]; K=512 split across halves
        {
            const int c = tid & 255, kg = tid >> 8;
            const int o = kg * 256;
            float acc = (kg == 0) ? st_b2[c] : 0.f;
            const float* wp = st_w2 + (size_t)o * 256 + c;
            #pragma unroll 4
            for (int d = 0; d < 256; d += 4) {
                float w0 = wp[(size_t)(d + 0) * 256], w1 = wp[(size_t)(d + 1) * 256];
                float w2 = wp[(size_t)(d + 2) * 256], w3 = wp[(size_t)(d + 3) * 256];
                float4 s = *(const float4*)&hid_s[o + d];
                acc += s.x * w0 + s.y * w1 + s.z * w2 + s.w * w3;
            }
            ps[kg][c] = acc;
        }
        __syncthreads();
        if (tid < 256)
            sh[(size_t)b * 256 + tid] = ps[0][tid] + ps[1][tid];
    } else {
        const int r = blk - 64;
        if (tid < 64)
            ((float4*)h_s)[tid] = ((const float4*)(rank_emb + (size_t)r * 256))[tid];
        __syncthreads();
        {
            const int c = tid & 255, kh = tid >> 8;
            const int o = kh * 128;
            float acc = (kh == 0) ? rm_b1[r * 256 + c] : 0.f;
            const float* wb = rm_w1 + ((size_t)r * 512 + 256 + o) * 256 + c;
            #pragma unroll 4
            for (int d = 0; d < 128; d += 4) {
                float w0 = wb[(size_t)(d + 0) * 256], w1 = wb[(size_t)(d + 1) * 256];
                float w2 = wb[(size_t)(d + 2) * 256], w3 = wb[(size_t)(d + 3) * 256];
                float4 e = *(const float4*)&h_s[o + d];
                acc += e.x * w0 + e.y * w1 + e.z * w2 + e.w * w3;
            }
            ps[kh][c] = acc;
        }
        __syncthreads();
        if (tid < 256)
            re[(size_t)r * 256 + tid] = ps[0][tid] + ps[1][tid];
    }
}

// ---------- D1: mega-middle (R12 verbatim). 384 blocks x 512 thr.
// blk -> (r = blk%24, bt = blk/24), 4 batch rows per block; col = tid&255,
// rh = tid>>8. L3/L4: rh = K-half, acc[4] rows, LDS partials + combine.
// G2: rh = head, acc[4], full K=256. G3: 2-way K-split over 384 threads.
__global__ __launch_bounds__(512, 4) void mega_kernel(
    const float* __restrict__ sh,
    const float* __restrict__ re,
    const float* __restrict__ rm_w1,
    const float* __restrict__ rm_w2, const float* __restrict__ rm_b2,
    const float* __restrict__ mx_w1, const float* __restrict__ mx_b1,
    const float* __restrict__ mx_w2, const float* __restrict__ mx_b2,
    const float* __restrict__ my_w1, const float* __restrict__ my_b1,
    const float* __restrict__ my_w2, const float* __restrict__ my_b2,
    const float* __restrict__ ax_w1, const float* __restrict__ ax_b1,
    const float* __restrict__ ax_w2, const float* __restrict__ ax_b2,
    const float* __restrict__ ay_w1, const float* __restrict__ ay_b1,
    const float* __restrict__ ay_w2, const float* __restrict__ ay_b2,
    float* __restrict__ Pcat)
{
    __shared__ __align__(16) float sh_s[4][256];
    __shared__ __align__(16) float hdn_s[4][256];
    __shared__ __align__(16) float rf_s[4][256];
    __shared__ __align__(16) float hc_s[2][4][256];
    __shared__ __align__(16) float ps[2][4][256];
    __shared__ __align__(16) float re_s[256];
    const int tid = threadIdx.x;
    const int blk = blockIdx.x;
    const int r = blk % 24;          // blk % 8 == r % 8: rank stays on one XCD
    const int bt = blk / 24;         // 0..15
    const int b0 = bt * 4;
    const int col = tid & 255, rh = tid >> 8;

    if (tid < 256) {
        ((float4*)sh_s)[tid] = ((const float4*)sh)[(size_t)b0 * 64 + tid];
    } else if (tid < 320) {
        int j4 = tid - 256;
        ((float4*)re_s)[j4] = ((const float4*)re)[(size_t)r * 64 + j4];
    }
    __syncthreads();

    // L3 partial: K-half rh of sh @ rm_w1[r, :256, :], 4 rows
    {
        float a0 = 0.f, a1 = 0.f, a2 = 0.f, a3 = 0.f;
        const int o = rh * 128;
        const float* wp = rm_w1 + ((size_t)r * 512 + o) * 256 + col;
        #pragma unroll 4
        for (int d = 0; d < 128; d += 4) {
            float w0 = wp[(size_t)(d + 0) * 256], w1 = wp[(size_t)(d + 1) * 256];
            float w2 = wp[(size_t)(d + 2) * 256], w3 = wp[(size_t)(d + 3) * 256];
            float4 s0 = *(const float4*)&sh_s[0][o + d];
            float4 s1 = *(const float4*)&sh_s[1][o + d];
            float4 s2 = *(const float4*)&sh_s[2][o + d];
            float4 s3 = *(const float4*)&sh_s[3][o + d];
            a0 += s0.x * w0 + s0.y * w1 + s0.z * w2 + s0.w * w3;
            a1 += s1.x * w0 + s1.y * w1 + s1.z * w2 + s1.w * w3;
            a2 += s2.x * w0 + s2.y * w1 + s2.z * w2 + s2.w * w3;
            a3 += s3.x * w0 + s3.y * w1 + s3.z * w2 + s3.w * w3;
        }
        ps[rh][0][col] = a0; ps[rh][1][col] = a1;
        ps[rh][2][col] = a2; ps[rh][3][col] = a3;
    }
    __syncthreads();
    #pragma unroll
    for (int t = 0; t < 2; ++t) {
        int o2 = tid + t * 512;
        int i = o2 >> 8, c = o2 & 255;
        hdn_s[i][c] = leaky(re_s[c] + ps[0][i][c] + ps[1][i][c]);
    }
    __syncthreads();

    // L4 partial: K-half rh of hdn @ rm_w2[r], 4 rows
    {
        float a0 = 0.f, a1 = 0.f, a2 = 0.f, a3 = 0.f;
        const int o = rh * 128;
        const float* wp = rm_w2 + (size_t)r * 65536 + (size_t)o * 256 + col;
        #pragma unroll 4
        for (int d = 0; d < 128; d += 4) {
            float w0 = wp[(size_t)(d + 0) * 256], w1 = wp[(size_t)(d + 1) * 256];
            float w2 = wp[(size_t)(d + 2) * 256], w3 = wp[(size_t)(d + 3) * 256];
            float4 s0 = *(const float4*)&hdn_s[0][o + d];
            float4 s1 = *(const float4*)&hdn_s[1][o + d];
            float4 s2 = *(const float4*)&hdn_s[2][o + d];
            float4 s3 = *(const float4*)&hdn_s[3][o + d];
            a0 += s0.x * w0 + s0.y * w1 + s0.z * w2 + s0.w * w3;
            a1 += s1.x * w0 + s1.y * w1 + s1.z * w2 + s1.w * w3;
            a2 += s2.x * w0 + s2.y * w1 + s2.z * w2 + s2.w * w3;
            a3 += s3.x * w0 + s3.y * w1 + s3.z * w2 + s3.w * w3;
        }
        ps[rh][0][col] = a0; ps[rh][1][col] = a1;
        ps[rh][2][col] = a2; ps[rh][3][col] = a3;
    }
    __syncthreads();
    #pragma unroll
    for (int t = 0; t < 2; ++t) {
        int o2 = tid + t * 512;
        int i = o2 >> 8, c = o2 & 255;
        rf_s[i][c] = rm_b2[r * 256 + c] + ps[0][i][c] + ps[1][i][c];
    }
    __syncthreads();

    const float *W1, *B1, *W2_0, *B2_0, *W2_1, *B2_1; int y0, y1;
    if (r < 16) {
        y0 = r;       y1 = 16 + r;
        W2_0 = mx_w2 + (size_t)r * 6144;  B2_0 = mx_b2 + r * 24;
        W2_1 = my_w2 + (size_t)r * 6144;  B2_1 = my_b2 + r * 24;
        W1 = (rh == 0) ? mx_w1 + (size_t)r * 65536 : my_w1 + (size_t)r * 65536;
        B1 = (rh == 0) ? mx_b1 + r * 256           : my_b1 + r * 256;
    } else {
        int rw = r - 16;
        y0 = 32 + rw;  y1 = 40 + rw;
        W2_0 = ax_w2 + (size_t)rw * 6144; B2_0 = ax_b2 + rw * 24;
        W2_1 = ay_w2 + (size_t)rw * 6144; B2_1 = ay_b2 + rw * 24;
        W1 = (rh == 0) ? ax_w1 + (size_t)rw * 65536 : ay_w1 + (size_t)rw * 65536;
        B1 = (rh == 0) ? ax_b1 + rw * 256           : ay_b1 + rw * 256;
    }

    // G2 (head rh): hc[rh] = leaky(rf @ W1 + B1), all 4 rows, K=256
    {
        float bv = B1[col];
        float acc0 = bv, acc1 = bv, acc2 = bv, acc3 = bv;
        const float* wp = W1 + col;
        #pragma unroll 4
        for (int d = 0; d < 256; d += 4) {
            float w0 = wp[(size_t)(d + 0) * 256], w1 = wp[(size_t)(d + 1) * 256];
            float w2 = wp[(size_t)(d + 2) * 256], w3 = wp[(size_t)(d + 3) * 256];
            float4 s0 = *(const float4*)&rf_s[0][d];
            float4 s1 = *(const float4*)&rf_s[1][d];
            float4 s2 = *(const float4*)&rf_s[2][d];
            float4 s3 = *(const float4*)&rf_s[3][d];
            acc0 += s0.x * w0 + s0.y * w1 + s0.z * w2 + s0.w * w3;
            acc1 += s1.x * w0 + s1.y * w1 + s1.z * w2 + s1.w * w3;
            acc2 += s2.x * w0 + s2.y * w1 + s2.z * w2 + s2.w * w3;
            acc3 += s3.x * w0 + s3.y * w1 + s3.z * w2 + s3.w * w3;
        }
        hc_s[rh][0][col] = leaky(acc0); hc_s[rh][1][col] = leaky(acc1);
        hc_s[rh][2][col] = leaky(acc2); hc_s[rh][3][col] = leaky(acc3);
    }
    __syncthreads();

    float* psf = &ps[0][0][0];
    if (tid < 384) {
        int o = tid >> 1, kq = tid & 1;
        int h2 = o / 96, rc = o % 96;
        int row = rc / 24, cj = rc - row * 24;
        const float* wp = (h2 ? W2_1 : W2_0) + (size_t)(kq * 128) * 24 + cj;
        const float* hp = &hc_s[h2][row][kq * 128];
        float acc = 0.f;
        #pragma unroll 4
        for (int d = 0; d < 128; d += 4) {
            float w0 = wp[(d + 0) * 24], w1 = wp[(d + 1) * 24];
            float w2 = wp[(d + 2) * 24], w3 = wp[(d + 3) * 24];
            float4 s = *(const float4*)&hp[d];
            acc += s.x * w0 + s.y * w1 + s.z * w2 + s.w * w3;
        }
        psf[tid] = acc;
    }
    __syncthreads();
    if (tid < 192) {
        int h2 = tid / 96, rc = tid - h2 * 96;
        int row = rc / 24, cj = rc - row * 24;
        float v = (h2 ? B2_1 : B2_0)[cj] + psf[tid * 2] + psf[tid * 2 + 1];
        int y = h2 ? y1 : y0;
        Pcat[(size_t)(b0 + row) * 1152 + y * 24 + cj] = v;
    }
}

// ---------- D2: fused spline + depth (unchanged).
// Pcat rows: [Px_m 0..15, Py_m 16..31, Px_a 32..39, Py_a 40..47]
__global__ __launch_bounds__(256, 2) void depth_fused_kernel(
    const float* __restrict__ Pcat,
    const float* __restrict__ mult_w, const float* __restrict__ addx_w,
    const float* __restrict__ addy_w, const float* __restrict__ gbias,
    float* __restrict__ out)
{
    __shared__ float cp[48][25];
    __shared__ float sw[33];
    __shared__ __align__(16) float u_s[16][132];
    __shared__ __align__(16) float v_s[16][132];
    __shared__ float dx_s[128], dy_s[128];
    const int tid = threadIdx.x;
    const int b = blockIdx.z, h0 = blockIdx.y * 128, w0 = blockIdx.x * 128;
    for (int idx = tid; idx < 1152; idx += 256)
        cp[idx / 24][idx % 24] = Pcat[(size_t)b * 1152 + idx];
    if (tid == 0) {
        float e[16], m, s;
        m = -1e30f; for (int i = 0; i < 16; ++i) m = fmaxf(m, mult_w[i]);
        s = 0.f;    for (int i = 0; i < 16; ++i) { e[i] = __expf(mult_w[i] - m); s += e[i]; }
        for (int i = 0; i < 16; ++i) sw[i] = e[i] / s;
        m = -1e30f; for (int i = 0; i < 8; ++i) m = fmaxf(m, addx_w[i]);
        s = 0.f;    for (int i = 0; i < 8; ++i) { e[i] = __expf(addx_w[i] - m); s += e[i]; }
        for (int i = 0; i < 8; ++i) sw[16 + i] = e[i] / s;
        m = -1e30f; for (int i = 0; i < 8; ++i) m = fmaxf(m, addy_w[i]);
        s = 0.f;    for (int i = 0; i < 8; ++i) { e[i] = __expf(addy_w[i] - m); s += e[i]; }
        for (int i = 0; i < 8; ++i) sw[24 + i] = e[i] / s;
        sw[32] = gbias[0];
    }
    __syncthreads();
    {
        const int local = tid & 127;
        const int gpos = (tid < 128 ? w0 : h0) + local;
        const float eps = 0.001f;
        float t = eps + (float)gpos * ((1.f - 2.f * eps) / 511.f);
        float ts = t * 23.f;
        int seg = (int)ts; if (seg > 22) seg = 22;
        float tau = ts - (float)seg;
        tau = fminf(fmaxf(tau, 0.f), 0.9999f);
        float t2 = tau * tau, t3 = t2 * tau;
        float h00 = 2.f * t3 - 3.f * t2 + 1.f;
        float h10 = t3 - 2.f * t2 + tau;
        float h01 = -2.f * t3 + 3.f * t2;
        float h11 = t3 - t2;
        int sm1 = seg > 0 ? seg - 1 : 0;
        int s1 = seg + 1;
        int sp2 = s1 < 23 ? s1 + 1 : 23;
        const float msc = 0.5f / 23.f;
        auto spl = [&](int row) -> float {
            float pk = cp[row][seg], pk1 = cp[row][s1];
            float mk  = msc * (pk1 - cp[row][sm1]);
            float mk1 = msc * (cp[row][sp2] - pk);
            return h00 * pk + h10 * mk + h01 * pk1 + h11 * mk1;
        };
        if (tid < 128) {
            #pragma unroll
            for (int r = 0; r < 16; ++r) u_s[r][local] = sw[r] * spl(r);
            float dx = sw[32];
            #pragma unroll
            for (int r = 0; r < 8; ++r) dx += sw[16 + r] * spl(32 + r);
            dx_s[local] = dx;
        } else {
            #pragma unroll
            for (int r = 0; r < 16; ++r) v_s[r][local] = spl(16 + r);
            float dy = 0.f;
            #pragma unroll
            for (int r = 0; r < 8; ++r) dy += sw[24 + r] * spl(40 + r);
            dy_s[local] = dy;
        }
    }
    __syncthreads();
    const int tw = tid & 15, th = tid >> 4;
    float acc[8][8];
    #pragma unroll
    for (int i = 0; i < 8; ++i)
        #pragma unroll
        for (int j = 0; j < 8; ++j) acc[i][j] = 0.f;
    #pragma unroll
    for (int r = 0; r < 16; ++r) {
        float4 va0 = *(const float4*)&v_s[r][th * 8];
        float4 va1 = *(const float4*)&v_s[r][th * 8 + 4];
        float4 ub0 = *(const float4*)&u_s[r][tw * 8];
        float4 ub1 = *(const float4*)&u_s[r][tw * 8 + 4];
        float va[8] = {va0.x, va0.y, va0.z, va0.w, va1.x, va1.y, va1.z, va1.w};
        float ub[8] = {ub0.x, ub0.y, ub0.z, ub0.w, ub1.x, ub1.y, ub1.z, ub1.w};
        #pragma unroll
        for (int i = 0; i < 8; ++i)
            #pragma unroll
            for (int j = 0; j < 8; ++j)
                acc[i][j] += va[i] * ub[j];
    }
    #pragma unroll
    for (int i = 0; i < 8; ++i) {
        float dyh = dy_s[th * 8 + i];
        float* op = out + (size_t)b * 262144 + (size_t)(h0 + th * 8 + i) * 512 + w0 + tw * 8;
        float4 o0, o1;
        o0.x = acc[i][0] + dx_s[tw * 8 + 0] + dyh;
        o0.y = acc[i][1] + dx_s[tw * 8 + 1] + dyh;
        o0.z = acc[i][2] + dx_s[tw * 8 + 2] + dyh;
        o0.w = acc[i][3] + dx_s[tw * 8 + 3] + dyh;
        o1.x = acc[i][4] + dx_s[tw * 8 + 4] + dyh;
        o1.y = acc[i][5] + dx_s[tw * 8 + 5] + dyh;
        o1.z = acc[i][6] + dx_s[tw * 8 + 6] + dyh;
        o1.w = acc[i][7] + dx_s[tw * 8 + 7] + dyh;
        *(float4*)op = o0;
        *(float4*)(op + 4) = o1;
    }
}

// ---------- host ----------
extern "C" void kernel_launch(void* const* d_in, const int* in_sizes, int n_in,
                              void* d_out, int out_size, void* d_ws, size_t ws_size,
                              hipStream_t stream) {
    const float* in_h     = (const float*)d_in[0];
    const float* rank_emb = (const float*)d_in[1];
    const float* st_w1    = (const float*)d_in[2];
    const float* st_b1    = (const float*)d_in[3];
    const float* st_w2    = (const float*)d_in[4];
    const float* st_b2    = (const float*)d_in[5];
    const float* rm_w1    = (const float*)d_in[6];
    const float* rm_b1    = (const float*)d_in[7];
    const float* rm_w2    = (const float*)d_in[8];
    const float* rm_b2    = (const float*)d_in[9];
    const float* mx_w1    = (const float*)d_in[10];
    const float* mx_b1    = (const float*)d_in[11];
    const float* mx_w2    = (const float*)d_in[12];
    const float* mx_b2    = (const float*)d_in[13];
    const float* my_w1    = (const float*)d_in[14];
    const float* my_b1    = (const float*)d_in[15];
    const float* my_w2    = (const float*)d_in[16];
    const float* my_b2    = (const float*)d_in[17];
    const float* ax_w1    = (const float*)d_in[18];
    const float* ax_b1    = (const float*)d_in[19];
    const float* ax_w2    = (const float*)d_in[20];
    const float* ax_b2    = (const float*)d_in[21];
    const float* ay_w1    = (const float*)d_in[22];
    const float* ay_b1    = (const float*)d_in[23];
    const float* ay_w2    = (const float*)d_in[24];
    const float* ay_b2    = (const float*)d_in[25];
    const float* mult_w   = (const float*)d_in[26];
    const float* addx_w   = (const float*)d_in[27];
    const float* addy_w   = (const float*)d_in[28];
    const float* gbias    = (const float*)d_in[29];
    (void)in_sizes; (void)n_in; (void)out_size; (void)ws_size;

    float* ws = (float*)d_ws;
    float* Pcat  = ws;               // 64x48x24 = 73728 floats
    float* shbuf = ws + 73728;       // 64x256   = 16384 floats
    float* rebuf = ws + 90112;       // 24x256   = 6144 floats

    // D0: shared MLP (L1+L2 fused, per-batch-row) + prebias
    shared_kernel<<<88, 512, 0, stream>>>(in_h, st_w1, st_b1, st_w2, st_b2,
                                          rank_emb, rm_w1, rm_b1, shbuf, rebuf);

    // D1: mega-middle -> Pcat (384 blocks, XCD-clustered by rank)
    mega_kernel<<<384, 512, 0, stream>>>(
        shbuf, rebuf,
        rm_w1, rm_w2, rm_b2,
        mx_w1, mx_b1, mx_w2, mx_b2,
        my_w1, my_b1, my_w2, my_b2,
        ax_w1, ax_b1, ax_w2, ax_b2,
        ay_w1, ay_b1, ay_w2, ay_b2,
        Pcat);

    // D2: fused spline + depth
    depth_fused_kernel<<<dim3(4, 4, 64), 256, 0, stream>>>(
        Pcat, mult_w, addx_w, addy_w, gbias, (float*)d_out);
}

// Round 8
// 236.149 us; speedup vs baseline: 1.0112x; 1.0112x over previous
//
#include <hip/hip_runtime.h>

// All inputs and the output are float32 (established rounds 0-3).
// R15: R13/R14 refuted the dispatch-overhead theory (4->3 dispatches: no change;
// ~140us is harness-side). mega (68us) is concurrency-bound: 27% occupancy, all
// blocks co-resident, 128-256-deep serial L2 load chains, L2-BW floor only ~12us.
// Fix: 1024-thr mega over the SAME 4 rows (no weight-traffic duplication):
// K-quartered L3/L4 (chains 128->64), G2 head x K-half, G3 4-way split. Per-thread
// phase bodies stay R12's no-spill shape (acc[4], unroll 4); launch_bounds(1024,8)
// pins VGPR<=64 so 2 blocks/CU co-reside (LDS 37KB). shared_kernel -> 1024 thr
// (L1 chain 768->384). depth unchanged. Tripwire: mega WRITE_SIZE must stay 288KB.

__device__ __forceinline__ float leaky(float v) { return v >= 0.f ? v : 0.2f * v; }

// ---------- D0: shared MLP + prebias. 88 blocks x 1024 thr.
// blocks 0..63 (b=blk): sh[b] = leaky(h[b] @ st_w1 + st_b1) @ st_w2 + st_b2
// blocks 64..87 (r=blk-64): re[r] = rm_b1[r] + rank_emb[r] @ rm_w1[r, 256:, :]
__global__ __launch_bounds__(1024, 4) void shared_kernel(
    const float* __restrict__ h,
    const float* __restrict__ st_w1, const float* __restrict__ st_b1,
    const float* __restrict__ st_w2, const float* __restrict__ st_b2,
    const float* __restrict__ rank_emb,
    const float* __restrict__ rm_w1, const float* __restrict__ rm_b1,
    float* __restrict__ sh, float* __restrict__ re)
{
    __shared__ __align__(16) float h_s[768];
    __shared__ __align__(16) float hid_s[512];
    __shared__ __align__(16) float ps[4][512];
    const int tid = threadIdx.x;
    const int blk = blockIdx.x;
    if (blk < 64) {
        const int b = blk;
        if (tid < 192)
            ((float4*)h_s)[tid] = ((const float4*)(h + (size_t)b * 768))[tid];
        __syncthreads();
        // L1: hid cols 512 x 2 K-halves (384 each); dual acc, 16 loads in flight
        {
            const int c = tid & 511, kh = tid >> 9;
            const int o = kh * 384;
            float acc0 = 0.f, acc1 = 0.f;
            const float* wp = st_w1 + (size_t)o * 512 + c;
            #pragma unroll 2
            for (int k = 0; k < 384; k += 8) {
                float w0 = wp[(size_t)(k + 0) * 512], w1 = wp[(size_t)(k + 1) * 512];
                float w2 = wp[(size_t)(k + 2) * 512], w3 = wp[(size_t)(k + 3) * 512];
                float4 hv0 = *(const float4*)&h_s[o + k];
                float w4 = wp[(size_t)(k + 4) * 512], w5 = wp[(size_t)(k + 5) * 512];
                float w6 = wp[(size_t)(k + 6) * 512], w7 = wp[(size_t)(k + 7) * 512];
                float4 hv1 = *(const float4*)&h_s[o + k + 4];
                acc0 += hv0.x * w0 + hv0.y * w1 + hv0.z * w2 + hv0.w * w3;
                acc1 += hv1.x * w4 + hv1.y * w5 + hv1.z * w6 + hv1.w * w7;
            }
            ps[kh][c] = acc0 + acc1;
        }
        __syncthreads();
        if (tid < 512)
            hid_s[tid] = leaky(st_b1[tid] + ps[0][tid] + ps[1][tid]);
        __syncthreads();
        // L2: 256 cols x 4 K-quarters (128 each)
        {
            const int c = tid & 255, kq = tid >> 8;
            const int o = kq * 128;
            float acc = 0.f;
            const float* wp = st_w2 + (size_t)o * 256 + c;
            #pragma unroll 4
            for (int d = 0; d < 128; d += 4) {
                float w0 = wp[(size_t)(d + 0) * 256], w1 = wp[(size_t)(d + 1) * 256];
                float w2 = wp[(size_t)(d + 2) * 256], w3 = wp[(size_t)(d + 3) * 256];
                float4 s = *(const float4*)&hid_s[o + d];
                acc += s.x * w0 + s.y * w1 + s.z * w2 + s.w * w3;
            }
            ps[kq][c] = acc;
        }
        __syncthreads();
        if (tid < 256)
            sh[(size_t)b * 256 + tid] = st_b2[tid]
                + ps[0][tid] + ps[1][tid] + ps[2][tid] + ps[3][tid];
    } else {
        const int r = blk - 64;
        if (tid < 64)
            ((float4*)h_s)[tid] = ((const float4*)(rank_emb + (size_t)r * 256))[tid];
        __syncthreads();
        // prebias: 256 cols x 4 K-quarters (64 each)
        {
            const int c = tid & 255, kq = tid >> 8;
            const int o = kq * 64;
            float acc = 0.f;
            const float* wb = rm_w1 + ((size_t)r * 512 + 256 + o) * 256 + c;
            #pragma unroll 4
            for (int d = 0; d < 64; d += 4) {
                float w0 = wb[(size_t)(d + 0) * 256], w1 = wb[(size_t)(d + 1) * 256];
                float w2 = wb[(size_t)(d + 2) * 256], w3 = wb[(size_t)(d + 3) * 256];
                float4 e = *(const float4*)&h_s[o + d];
                acc += e.x * w0 + e.y * w1 + e.z * w2 + e.w * w3;
            }
            ps[kq][c] = acc;
        }
        __syncthreads();
        if (tid < 256)
            re[(size_t)r * 256 + tid] = rm_b1[r * 256 + tid]
                + ps[0][tid] + ps[1][tid] + ps[2][tid] + ps[3][tid];
    }
}

// ---------- D1: mega-middle. 384 blocks x 1024 thr. blk -> (r = blk%24, bt = blk/24),
// 4 batch rows per block; col = tid&255, sub = tid>>8 (0..3).
// L3/L4: sub = K-quarter (64 K), acc[4] rows, ps[4] partials + combine.
// G2: sub = (kh<<1)|h -> head h, K-half 128, acc[4]. G3: 4-way K-split, 768 thr.
// Per-thread bodies = R12's no-spill shape (acc[4], 4 w-regs, unroll 4).
__global__ __launch_bounds__(1024, 8) void mega_kernel(
    const float* __restrict__ sh,
    const float* __restrict__ re,
    const float* __restrict__ rm_w1,
    const float* __restrict__ rm_w2, const float* __restrict__ rm_b2,
    const float* __restrict__ mx_w1, const float* __restrict__ mx_b1,
    const float* __restrict__ mx_w2, const float* __restrict__ mx_b2,
    const float* __restrict__ my_w1, const float* __restrict__ my_b1,
    const float* __restrict__ my_w2, const float* __restrict__ my_b2,
    const float* __restrict__ ax_w1, const float* __restrict__ ax_b1,
    const float* __restrict__ ax_w2, const float* __restrict__ ax_b2,
    const float* __restrict__ ay_w1, const float* __restrict__ ay_b1,
    const float* __restrict__ ay_w2, const float* __restrict__ ay_b2,
    float* __restrict__ Pcat)
{
    __shared__ __align__(16) float sh_s[4][256];     // 4 KB
    __shared__ __align__(16) float hdn_s[4][256];    // 4 KB
    __shared__ __align__(16) float rf_s[4][256];     // 4 KB
    __shared__ __align__(16) float hc_s[2][4][256];  // 8 KB
    __shared__ __align__(16) float ps[4][4][256];    // 16 KB (reused as psf[768])
    __shared__ __align__(16) float re_s[256];        // 1 KB   (total 37 KB)
    const int tid = threadIdx.x;
    const int blk = blockIdx.x;
    const int r = blk % 24;          // blk % 8 == r % 8: rank stays on one XCD
    const int bt = blk / 24;         // 0..15
    const int b0 = bt * 4;
    const int col = tid & 255, sub = tid >> 8;

    // stage: 4 sh rows (256 float4) + re row (64 float4)
    if (tid < 256) {
        ((float4*)sh_s)[tid] = ((const float4*)sh)[(size_t)b0 * 64 + tid];
    } else if (tid < 320) {
        int j4 = tid - 256;
        ((float4*)re_s)[j4] = ((const float4*)re)[(size_t)r * 64 + j4];
    }
    __syncthreads();

    // L3 partial: K-quarter sub (64 K) of sh @ rm_w1[r, :256, :], 4 rows
    {
        float a0 = 0.f, a1 = 0.f, a2 = 0.f, a3 = 0.f;
        const int o = sub * 64;
        const float* wp = rm_w1 + ((size_t)r * 512 + o) * 256 + col;
        #pragma unroll 4
        for (int d = 0; d < 64; d += 4) {
            float w0 = wp[(size_t)(d + 0) * 256], w1 = wp[(size_t)(d + 1) * 256];
            float w2 = wp[(size_t)(d + 2) * 256], w3 = wp[(size_t)(d + 3) * 256];
            float4 s0 = *(const float4*)&sh_s[0][o + d];
            float4 s1 = *(const float4*)&sh_s[1][o + d];
            float4 s2 = *(const float4*)&sh_s[2][o + d];
            float4 s3 = *(const float4*)&sh_s[3][o + d];
            a0 += s0.x * w0 + s0.y * w1 + s0.z * w2 + s0.w * w3;
            a1 += s1.x * w0 + s1.y * w1 + s1.z * w2 + s1.w * w3;
            a2 += s2.x * w0 + s2.y * w1 + s2.z * w2 + s2.w * w3;
            a3 += s3.x * w0 + s3.y * w1 + s3.z * w2 + s3.w * w3;
        }
        ps[sub][0][col] = a0; ps[sub][1][col] = a1;
        ps[sub][2][col] = a2; ps[sub][3][col] = a3;
    }
    __syncthreads();
    // combine: 1024 threads cover 4 rows x 256 cols
    {
        int i = tid >> 8, c = tid & 255;
        hdn_s[i][c] = leaky(re_s[c] + ps[0][i][c] + ps[1][i][c]
                                    + ps[2][i][c] + ps[3][i][c]);
    }
    __syncthreads();

    // L4 partial: K-quarter sub of hdn @ rm_w2[r], 4 rows
    {
        float a0 = 0.f, a1 = 0.f, a2 = 0.f, a3 = 0.f;
        const int o = sub * 64;
        const float* wp = rm_w2 + (size_t)r * 65536 + (size_t)o * 256 + col;
        #pragma unroll 4
        for (int d = 0; d < 64; d += 4) {
            float w0 = wp[(size_t)(d + 0) * 256], w1 = wp[(size_t)(d + 1) * 256];
            float w2 = wp[(size_t)(d + 2) * 256], w3 = wp[(size_t)(d + 3) * 256];
            float4 s0 = *(const float4*)&hdn_s[0][o + d];
            float4 s1 = *(const float4*)&hdn_s[1][o + d];
            float4 s2 = *(const float4*)&hdn_s[2][o + d];
            float4 s3 = *(const float4*)&hdn_s[3][o + d];
            a0 += s0.x * w0 + s0.y * w1 + s0.z * w2 + s0.w * w3;
            a1 += s1.x * w0 + s1.y * w1 + s1.z * w2 + s1.w * w3;
            a2 += s2.x * w0 + s2.y * w1 + s2.z * w2 + s2.w * w3;
            a3 += s3.x * w0 + s3.y * w1 + s3.z * w2 + s3.w * w3;
        }
        ps[sub][0][col] = a0; ps[sub][1][col] = a1;
        ps[sub][2][col] = a2; ps[sub][3][col] = a3;
    }
    __syncthreads();
    {
        int i = tid >> 8, c = tid & 255;
        rf_s[i][c] = rm_b2[r * 256 + c] + ps[0][i][c] + ps[1][i][c]
                                        + ps[2][i][c] + ps[3][i][c];
    }
    __syncthreads();

    // head pointers: r<16: head0=mx(y=r), head1=my(y=16+r);
    // r>=16: rw=r-16: head0=ax(y=32+rw), head1=ay(y=40+rw)
    const float *W1_0, *B1_0, *W2_0, *B2_0, *W1_1, *B1_1, *W2_1, *B2_1;
    int y0, y1;
    if (r < 16) {
        y0 = r;       y1 = 16 + r;
        W1_0 = mx_w1 + (size_t)r * 65536;  B1_0 = mx_b1 + r * 256;
        W2_0 = mx_w2 + (size_t)r * 6144;   B2_0 = mx_b2 + r * 24;
        W1_1 = my_w1 + (size_t)r * 65536;  B1_1 = my_b1 + r * 256;
        W2_1 = my_w2 + (size_t)r * 6144;   B2_1 = my_b2 + r * 24;
    } else {
        int rw = r - 16;
        y0 = 32 + rw;  y1 = 40 + rw;
        W1_0 = ax_w1 + (size_t)rw * 65536; B1_0 = ax_b1 + rw * 256;
        W2_0 = ax_w2 + (size_t)rw * 6144;  B2_0 = ax_b2 + rw * 24;
        W1_1 = ay_w1 + (size_t)rw * 65536; B1_1 = ay_b1 + rw * 256;
        W2_1 = ay_w2 + (size_t)rw * 6144;  B2_1 = ay_b2 + rw * 24;
    }

    // G2 partial: sub = (kh<<1)|h -> head h, K-half kh (128), acc[4]
    {
        const int hh = sub & 1, kh = sub >> 1;
        const int o = kh * 128;
        const float* wp = (hh ? W1_1 : W1_0) + (size_t)o * 256 + col;
        float a0 = 0.f, a1 = 0.f, a2 = 0.f, a3 = 0.f;
        #pragma unroll 4
        for (int d = 0; d < 128; d += 4) {
            float w0 = wp[(size_t)(d + 0) * 256], w1 = wp[(size_t)(d + 1) * 256];
            float w2 = wp[(size_t)(d + 2) * 256], w3 = wp[(size_t)(d + 3) * 256];
            float4 s0 = *(const float4*)&rf_s[0][o + d];
            float4 s1 = *(const float4*)&rf_s[1][o + d];
            float4 s2 = *(const float4*)&rf_s[2][o + d];
            float4 s3 = *(const float4*)&rf_s[3][o + d];
            a0 += s0.x * w0 + s0.y * w1 + s0.z * w2 + s0.w * w3;
            a1 += s1.x * w0 + s1.y * w1 + s1.z * w2 + s1.w * w3;
            a2 += s2.x * w0 + s2.y * w1 + s2.z * w2 + s2.w * w3;
            a3 += s3.x * w0 + s3.y * w1 + s3.z * w2 + s3.w * w3;
        }
        ps[sub][0][col] = a0; ps[sub][1][col] = a1;
        ps[sub][2][col] = a2; ps[sub][3][col] = a3;
    }
    __syncthreads();
    // combine hc: 2 heads x 4 rows x 256 cols = 2048 entries over 1024 thr
    #pragma unroll
    for (int t = 0; t < 2; ++t) {
        int idx = tid + t * 1024;
        int h2 = idx >> 10, rem = idx & 1023;
        int i = rem >> 8, c = rem & 255;
        hc_s[h2][i][c] = leaky((h2 ? B1_1 : B1_0)[c]
                               + ps[h2][i][c] + ps[2 + h2][i][c]);
    }
    __syncthreads();

    // G3 partial: 2 heads x 4 rows x 24 cols x 4 K-quarters(64) = 768 threads
    float* psf = &ps[0][0][0];
    if (tid < 768) {
        int o = tid >> 2, kq = tid & 3;
        int h2 = o / 96, rc = o % 96;
        int row = rc / 24, cj = rc - row * 24;
        const float* wp = (h2 ? W2_1 : W2_0) + (size_t)(kq * 64) * 24 + cj;
        const float* hp = &hc_s[h2][row][kq * 64];
        float acc = 0.f;
        #pragma unroll 4
        for (int d = 0; d < 64; d += 4) {
            float w0 = wp[(d + 0) * 24], w1 = wp[(d + 1) * 24];
            float w2 = wp[(d + 2) * 24], w3 = wp[(d + 3) * 24];
            float4 s = *(const float4*)&hp[d];
            acc += s.x * w0 + s.y * w1 + s.z * w2 + s.w * w3;
        }
        psf[tid] = acc;
    }
    __syncthreads();
    if (tid < 192) {
        int h2 = tid / 96, rc = tid - h2 * 96;
        int row = rc / 24, cj = rc - row * 24;
        float v = (h2 ? B2_1 : B2_0)[cj]
                + psf[tid * 4] + psf[tid * 4 + 1] + psf[tid * 4 + 2] + psf[tid * 4 + 3];
        int y = h2 ? y1 : y0;
        Pcat[(size_t)(b0 + row) * 1152 + y * 24 + cj] = v;
    }
}

// ---------- D2: fused spline + depth (unchanged).
// Pcat rows: [Px_m 0..15, Py_m 16..31, Px_a 32..39, Py_a 40..47]
__global__ __launch_bounds__(256, 2) void depth_fused_kernel(
    const float* __restrict__ Pcat,
    const float* __restrict__ mult_w, const float* __restrict__ addx_w,
    const float* __restrict__ addy_w, const float* __restrict__ gbias,
    float* __restrict__ out)
{
    __shared__ float cp[48][25];
    __shared__ float sw[33];
    __shared__ __align__(16) float u_s[16][132];
    __shared__ __align__(16) float v_s[16][132];
    __shared__ float dx_s[128], dy_s[128];
    const int tid = threadIdx.x;
    const int b = blockIdx.z, h0 = blockIdx.y * 128, w0 = blockIdx.x * 128;
    for (int idx = tid; idx < 1152; idx += 256)
        cp[idx / 24][idx % 24] = Pcat[(size_t)b * 1152 + idx];
    if (tid == 0) {
        float e[16], m, s;
        m = -1e30f; for (int i = 0; i < 16; ++i) m = fmaxf(m, mult_w[i]);
        s = 0.f;    for (int i = 0; i < 16; ++i) { e[i] = __expf(mult_w[i] - m); s += e[i]; }
        for (int i = 0; i < 16; ++i) sw[i] = e[i] / s;
        m = -1e30f; for (int i = 0; i < 8; ++i) m = fmaxf(m, addx_w[i]);
        s = 0.f;    for (int i = 0; i < 8; ++i) { e[i] = __expf(addx_w[i] - m); s += e[i]; }
        for (int i = 0; i < 8; ++i) sw[16 + i] = e[i] / s;
        m = -1e30f; for (int i = 0; i < 8; ++i) m = fmaxf(m, addy_w[i]);
        s = 0.f;    for (int i = 0; i < 8; ++i) { e[i] = __expf(addy_w[i] - m); s += e[i]; }
        for (int i = 0; i < 8; ++i) sw[24 + i] = e[i] / s;
        sw[32] = gbias[0];
    }
    __syncthreads();
    {
        const int local = tid & 127;
        const int gpos = (tid < 128 ? w0 : h0) + local;
        const float eps = 0.001f;
        float t = eps + (float)gpos * ((1.f - 2.f * eps) / 511.f);
        float ts = t * 23.f;
        int seg = (int)ts; if (seg > 22) seg = 22;
        float tau = ts - (float)seg;
        tau = fminf(fmaxf(tau, 0.f), 0.9999f);
        float t2 = tau * tau, t3 = t2 * tau;
        float h00 = 2.f * t3 - 3.f * t2 + 1.f;
        float h10 = t3 - 2.f * t2 + tau;
        float h01 = -2.f * t3 + 3.f * t2;
        float h11 = t3 - t2;
        int sm1 = seg > 0 ? seg - 1 : 0;
        int s1 = seg + 1;
        int sp2 = s1 < 23 ? s1 + 1 : 23;
        const float msc = 0.5f / 23.f;
        auto spl = [&](int row) -> float {
            float pk = cp[row][seg], pk1 = cp[row][s1];
            float mk  = msc * (pk1 - cp[row][sm1]);
            float mk1 = msc * (cp[row][sp2] - pk);
            return h00 * pk + h10 * mk + h01 * pk1 + h11 * mk1;
        };
        if (tid < 128) {
            #pragma unroll
            for (int r = 0; r < 16; ++r) u_s[r][local] = sw[r] * spl(r);
            float dx = sw[32];
            #pragma unroll
            for (int r = 0; r < 8; ++r) dx += sw[16 + r] * spl(32 + r);
            dx_s[local] = dx;
        } else {
            #pragma unroll
            for (int r = 0; r < 16; ++r) v_s[r][local] = spl(16 + r);
            float dy = 0.f;
            #pragma unroll
            for (int r = 0; r < 8; ++r) dy += sw[24 + r] * spl(40 + r);
            dy_s[local] = dy;
        }
    }
    __syncthreads();
    const int tw = tid & 15, th = tid >> 4;
    float acc[8][8];
    #pragma unroll
    for (int i = 0; i < 8; ++i)
        #pragma unroll
        for (int j = 0; j < 8; ++j) acc[i][j] = 0.f;
    #pragma unroll
    for (int r = 0; r < 16; ++r) {
        float4 va0 = *(const float4*)&v_s[r][th * 8];
        float4 va1 = *(const float4*)&v_s[r][th * 8 + 4];
        float4 ub0 = *(const float4*)&u_s[r][tw * 8];
        float4 ub1 = *(const float4*)&u_s[r][tw * 8 + 4];
        float va[8] = {va0.x, va0.y, va0.z, va0.w, va1.x, va1.y, va1.z, va1.w};
        float ub[8] = {ub0.x, ub0.y, ub0.z, ub0.w, ub1.x, ub1.y, ub1.z, ub1.w};
        #pragma unroll
        for (int i = 0; i < 8; ++i)
            #pragma unroll
            for (int j = 0; j < 8; ++j)
                acc[i][j] += va[i] * ub[j];
    }
    #pragma unroll
    for (int i = 0; i < 8; ++i) {
        float dyh = dy_s[th * 8 + i];
        float* op = out + (size_t)b * 262144 + (size_t)(h0 + th * 8 + i) * 512 + w0 + tw * 8;
        float4 o0, o1;
        o0.x = acc[i][0] + dx_s[tw * 8 + 0] + dyh;
        o0.y = acc[i][1] + dx_s[tw * 8 + 1] + dyh;
        o0.z = acc[i][2] + dx_s[tw * 8 + 2] + dyh;
        o0.w = acc[i][3] + dx_s[tw * 8 + 3] + dyh;
        o1.x = acc[i][4] + dx_s[tw * 8 + 4] + dyh;
        o1.y = acc[i][5] + dx_s[tw * 8 + 5] + dyh;
        o1.z = acc[i][6] + dx_s[tw * 8 + 6] + dyh;
        o1.w = acc[i][7] + dx_s[tw * 8 + 7] + dyh;
        *(float4*)op = o0;
        *(float4*)(op + 4) = o1;
    }
}

// ---------- host ----------
extern "C" void kernel_launch(void* const* d_in, const int* in_sizes, int n_in,
                              void* d_out, int out_size, void* d_ws, size_t ws_size,
                              hipStream_t stream) {
    const float* in_h     = (const float*)d_in[0];
    const float* rank_emb = (const float*)d_in[1];
    const float* st_w1    = (const float*)d_in[2];
    const float* st_b1    = (const float*)d_in[3];
    const float* st_w2    = (const float*)d_in[4];
    const float* st_b2    = (const float*)d_in[5];
    const float* rm_w1    = (const float*)d_in[6];
    const float* rm_b1    = (const float*)d_in[7];
    const float* rm_w2    = (const float*)d_in[8];
    const float* rm_b2    = (const float*)d_in[9];
    const float* mx_w1    = (const float*)d_in[10];
    const float* mx_b1    = (const float*)d_in[11];
    const float* mx_w2    = (const float*)d_in[12];
    const float* mx_b2    = (const float*)d_in[13];
    const float* my_w1    = (const float*)d_in[14];
    const float* my_b1    = (const float*)d_in[15];
    const float* my_w2    = (const float*)d_in[16];
    const float* my_b2    = (const float*)d_in[17];
    const float* ax_w1    = (const float*)d_in[18];
    const float* ax_b1    = (const float*)d_in[19];
    const float* ax_w2    = (const float*)d_in[20];
    const float* ax_b2    = (const float*)d_in[21];
    const float* ay_w1    = (const float*)d_in[22];
    const float* ay_b1    = (const float*)d_in[23];
    const float* ay_w2    = (const float*)d_in[24];
    const float* ay_b2    = (const float*)d_in[25];
    const float* mult_w   = (const float*)d_in[26];
    const float* addx_w   = (const float*)d_in[27];
    const float* addy_w   = (const float*)d_in[28];
    const float* gbias    = (const float*)d_in[29];
    (void)in_sizes; (void)n_in; (void)out_size; (void)ws_size;

    float* ws = (float*)d_ws;
    float* Pcat  = ws;               // 64x48x24 = 73728 floats
    float* shbuf = ws + 73728;       // 64x256   = 16384 floats
    float* rebuf = ws + 90112;       // 24x256   = 6144 floats

    // D0: shared MLP (L1+L2 fused, per-batch-row) + prebias
    shared_kernel<<<88, 1024, 0, stream>>>(in_h, st_w1, st_b1, st_w2, st_b2,
                                           rank_emb, rm_w1, rm_b1, shbuf, rebuf);

    // D1: mega-middle -> Pcat (384 blocks x 1024 thr, XCD-clustered by rank)
    mega_kernel<<<384, 1024, 0, stream>>>(
        shbuf, rebuf,
        rm_w1, rm_w2, rm_b2,
        mx_w1, mx_b1, mx_w2, mx_b2,
        my_w1, my_b1, my_w2, my_b2,
        ax_w1, ax_b1, ax_w2, ax_b2,
        ay_w1, ay_b1, ay_w2, ay_b2,
        Pcat);

    // D2: fused spline + depth
    depth_fused_kernel<<<dim3(4, 4, 64), 256, 0, stream>>>(
        Pcat, mult_w, addx_w, addy_w, gbias, (float*)d_out);
}